// Round 17
// baseline (452.079 us; speedup 1.0000x reference)
//
#include <hip/hip_runtime.h>
#include <math.h>
#include <stdint.h>

constexpr int S  = 2048;
constexpr int H  = 4096;
constexpr int NH = 32;
constexpr int HD = 128;
constexpr int H3 = 3 * H;   // 12288

typedef unsigned short u16;
typedef __bf16 bf16x8 __attribute__((ext_vector_type(8)));
typedef float  f32x4  __attribute__((ext_vector_type(4)));
typedef unsigned short us8 __attribute__((ext_vector_type(8)));

// f32 -> bf16 (RNE) as raw u16
__device__ __forceinline__ u16 f2bf(float f) {
  uint32_t u = __float_as_uint(f);
  uint32_t r = (u + 0x7fff + ((u >> 16) & 1)) >> 16;
  return (u16)r;
}
__device__ __forceinline__ float bf2f(u16 u) {
  return __uint_as_float((uint32_t)u << 16);
}

// async global->LDS, 16B per lane. LDS dest = wave-uniform base + lane*16.
__device__ __forceinline__ void load_lds16(const void* g, void* l) {
  __builtin_amdgcn_global_load_lds(
      (__attribute__((address_space(1))) void*)(uintptr_t)g,
      (__attribute__((address_space(3))) void*)l,
      16, 0, 0);
}

#define SBAR0 __builtin_amdgcn_sched_barrier(0)

// ---------------------------------------------------------------------------
// Fused cast: w_qkv, hidden, w_dense f32 -> bf16 in ONE launch (grid-stride).
// ---------------------------------------------------------------------------
__global__ __launch_bounds__(256)
void cast_all(const float* __restrict__ w_qkv, const float* __restrict__ hidden,
              const float* __restrict__ w_dense, u16* __restrict__ wq,
              u16* __restrict__ hb, u16* __restrict__ wd) {
  constexpr int NQ  = H3 * H / 4;          // 12582912
  constexpr int NHd = S * H / 4;           // 2097152
  constexpr int ND  = H * H / 4;           // 4194304
  constexpr int NT  = NQ + NHd + ND;
  for (int i = blockIdx.x * 256 + threadIdx.x; i < NT; i += gridDim.x * 256) {
    const float4* src;
    ushort4* dst;
    int j = i;
    if (j < NQ)            { src = (const float4*)w_qkv;  dst = (ushort4*)wq; }
    else if (j < NQ + NHd) { j -= NQ; src = (const float4*)hidden; dst = (ushort4*)hb; }
    else                   { j -= NQ + NHd; src = (const float4*)w_dense; dst = (ushort4*)wd; }
    float4 v = src[j];
    ushort4 o;
    o.x = f2bf(v.x); o.y = f2bf(v.y); o.z = f2bf(v.z); o.w = f2bf(v.w);
    dst[j] = o;
  }
}

// ---------------------------------------------------------------------------
// m201-geometry GEMM (chunk A, measured 132us / 44.9% MfmaUtil): BM=BN=256,
// BK=64; 512 thr = 8 waves (2M x 4N), per-wave 128x64 (acc[8][4]). 2 LDS
// buffers (128 KiB), region-tracked staging into the buffer being read,
// vmcnt(8) boundary. STRIDE = output row stride.
// ---------------------------------------------------------------------------
template<int STRIDE, int OUT_BF16>
__global__ __launch_bounds__(512, 2)
void gemm256(const u16* __restrict__ A, const u16* __restrict__ W,
             const float* __restrict__ bias, void* __restrict__ Cout) {
  constexpr int K   = 4096;
  constexpr int NT  = K / 64;           // 64 K-tiles
  constexpr int NTM = 8;                // 2048 / 256 row-tiles
  constexpr int TB  = 65536;            // per-buffer: A 32K + B 32K
  __shared__ __attribute__((aligned(16))) unsigned char lds[2 * TB];
  const int tid = threadIdx.x, wave = tid >> 6, lane = tid & 63;
  const int l15 = lane & 15, l4 = lane >> 4;
  const int wr = wave >> 2, wc = wave & 3;

  const int nwg = gridDim.x, bid = blockIdx.x;
  const int cpx = nwg >> 3;
  const int swz = (bid & 7) * cpx + (bid >> 3);
  const int bx = swz / NTM, by = swz - bx * NTM;  // by-fast (column-major)
  const int bm = by * 256, bn = bx * 256;

  const int srow = lane >> 3;                     // 0..7
  const int sck  = ((lane & 7) ^ srow) * 8;       // inverse-swizzled source
  const u16* Abase = A + (size_t)(bm + srow) * K + sck;
  const u16* Wbase = W + (size_t)(bn + srow) * K + sck;

  auto stageU = [&](int tt, int u) {
    const int b = tt & 1;
    if (u < 4) {
      const int rb = u * 64 + wave * 8;
      load_lds16(Abase + (size_t)rb * K + tt * 64, &lds[b * TB + rb * 128]);
    } else {
      const int rb = (u - 4) * 64 + wave * 8;
      load_lds16(Wbase + (size_t)rb * K + tt * 64,
                 &lds[b * TB + 32768 + rb * 128]);
    }
  };

  f32x4 acc[8][4];
#pragma unroll
  for (int i = 0; i < 8; ++i)
#pragma unroll
    for (int j = 0; j < 4; ++j) acc[i][j] = (f32x4)0.f;

#pragma unroll
  for (int u = 0; u < 8; ++u) stageU(0, u);
#pragma unroll
  for (int u = 0; u < 8; ++u) stageU(1, u);
  asm volatile("s_waitcnt vmcnt(8)" ::: "memory");
  SBAR0;
  __builtin_amdgcn_s_barrier();

  const int arow = wr * 128 + l15;     // + mi*16
  const int brow = wc * 64 + l15;      // + ni*16
  const int ckx  = l15 & 7;

  bf16x8 af[4][2], bfA[2][2], bfB[2][2];

  for (int t = 0; t < NT; ++t) {
    const int b0 = (t & 1) * TB;
    const bool st = (t + 2 < NT);
    // ---- ph0: read af[0..3] (8) + bfA (4); no stage
#pragma unroll
    for (int mi = 0; mi < 4; ++mi)
#pragma unroll
      for (int ks = 0; ks < 2; ++ks)
        af[mi][ks] = *(const bf16x8*)&lds[b0 + (arow + mi * 16) * 128 +
                                          (((ks * 4 + l4) ^ ckx) * 16)];
#pragma unroll
    for (int ni = 0; ni < 2; ++ni)
#pragma unroll
      for (int ks = 0; ks < 2; ++ks)
        bfA[ni][ks] = *(const bf16x8*)&lds[b0 + 32768 + (brow + ni * 16) * 128 +
                                           (((ks * 4 + l4) ^ ckx) * 16)];
    SBAR0; __builtin_amdgcn_s_barrier();
    asm volatile("s_waitcnt lgkmcnt(0)" ::: "memory");
    SBAR0;
    __builtin_amdgcn_s_setprio(1);
#pragma unroll
    for (int ks = 0; ks < 2; ++ks)
#pragma unroll
      for (int mi = 0; mi < 4; ++mi)
#pragma unroll
        for (int ni = 0; ni < 2; ++ni)
          acc[mi][ni] = __builtin_amdgcn_mfma_f32_16x16x32_bf16(af[mi][ks], bfA[ni][ks], acc[mi][ni], 0, 0, 0);
    __builtin_amdgcn_s_setprio(0);
    SBAR0; __builtin_amdgcn_s_barrier();
    // ---- ph1: read bfB (4); stage A rows {0-63, 128-191} of t+2
#pragma unroll
    for (int ni = 0; ni < 2; ++ni)
#pragma unroll
      for (int ks = 0; ks < 2; ++ks)
        bfB[ni][ks] = *(const bf16x8*)&lds[b0 + 32768 + (brow + (ni + 2) * 16) * 128 +
                                           (((ks * 4 + l4) ^ ckx) * 16)];
    if (st) { stageU(t + 2, 0); stageU(t + 2, 2); }
    SBAR0; __builtin_amdgcn_s_barrier();
    asm volatile("s_waitcnt lgkmcnt(0)" ::: "memory");
    SBAR0;
    __builtin_amdgcn_s_setprio(1);
#pragma unroll
    for (int ks = 0; ks < 2; ++ks)
#pragma unroll
      for (int mi = 0; mi < 4; ++mi)
#pragma unroll
        for (int ni = 0; ni < 2; ++ni)
          acc[mi][ni + 2] = __builtin_amdgcn_mfma_f32_16x16x32_bf16(af[mi][ks], bfB[ni][ks], acc[mi][ni + 2], 0, 0, 0);
    __builtin_amdgcn_s_setprio(0);
    SBAR0; __builtin_amdgcn_s_barrier();
    // ---- ph2: read af[4..7] (8, overwrite af); stage B rows 0-127 of t+2
#pragma unroll
    for (int mi = 0; mi < 4; ++mi)
#pragma unroll
      for (int ks = 0; ks < 2; ++ks)
        af[mi][ks] = *(const bf16x8*)&lds[b0 + (arow + (mi + 4) * 16) * 128 +
                                          (((ks * 4 + l4) ^ ckx) * 16)];
    if (st) { stageU(t + 2, 4); stageU(t + 2, 5); }
    SBAR0; __builtin_amdgcn_s_barrier();
    asm volatile("s_waitcnt lgkmcnt(0)" ::: "memory");
    SBAR0;
    __builtin_amdgcn_s_setprio(1);
#pragma unroll
    for (int ks = 0; ks < 2; ++ks)
#pragma unroll
      for (int mi = 0; mi < 4; ++mi)
#pragma unroll
        for (int ni = 0; ni < 2; ++ni)
          acc[mi + 4][ni] = __builtin_amdgcn_mfma_f32_16x16x32_bf16(af[mi][ks], bfA[ni][ks], acc[mi + 4][ni], 0, 0, 0);
    __builtin_amdgcn_s_setprio(0);
    SBAR0; __builtin_amdgcn_s_barrier();
    // ---- ph3: no reads; stage A {64-127,192-255} + B {128-255}; MFMA
    if (st) { stageU(t + 2, 1); stageU(t + 2, 3); stageU(t + 2, 6); stageU(t + 2, 7); }
    SBAR0;
    __builtin_amdgcn_s_setprio(1);
#pragma unroll
    for (int ks = 0; ks < 2; ++ks)
#pragma unroll
      for (int mi = 0; mi < 4; ++mi)
#pragma unroll
        for (int ni = 0; ni < 2; ++ni)
          acc[mi + 4][ni + 2] = __builtin_amdgcn_mfma_f32_16x16x32_bf16(af[mi][ks], bfB[ni][ks], acc[mi + 4][ni + 2], 0, 0, 0);
    __builtin_amdgcn_s_setprio(0);
    if (t < NT - 2)       asm volatile("s_waitcnt vmcnt(8)" ::: "memory");
    else if (t == NT - 2) asm volatile("s_waitcnt vmcnt(0)" ::: "memory");
    SBAR0;
    if (t < NT - 1) __builtin_amdgcn_s_barrier();
  }

#pragma unroll
  for (int ni = 0; ni < 4; ++ni) {
    const int col = bn + wc * 64 + ni * 16 + l15;
    const float bv = bias[col];
#pragma unroll
    for (int mi = 0; mi < 8; ++mi) {
#pragma unroll
      for (int r = 0; r < 4; ++r) {
        const int row = bm + wr * 128 + mi * 16 + l4 * 4 + r;
        const float v = acc[mi][ni][r] + bv;
        if (OUT_BF16) ((u16*)Cout)[(size_t)row * STRIDE + col] = f2bf(v);
        else          ((float*)Cout)[(size_t)row * STRIDE + col] = v;
      }
    }
  }
}

// ---------------------------------------------------------------------------
// gemm256n: BM=256, BN=128, BK=64 -> 8 x 32 = 256 blocks for a 2048x4096
// output chunk (exact 1/CU packing). 8 waves (2M x 4N): per-wave 128x32
// (acc[8][2]); 2 phases x 16 MFMA per K-tile. 3 LDS buffers (144 KiB,
// A 32K + B 16K each), 6 stage calls/tile split 3+3, steady vmcnt(6)
// (t's 6 calls in flight at boundary -> t+1 resident), tail vmcnt(0).
// Same swizzle + by-fast XCD map as gemm256.
// ---------------------------------------------------------------------------
template<int STRIDE, int OUT_BF16>
__global__ __launch_bounds__(512, 2)
void gemm256n(const u16* __restrict__ A, const u16* __restrict__ W,
              const float* __restrict__ bias, void* __restrict__ Cout) {
  constexpr int K   = 4096;
  constexpr int NT  = K / 64;
  constexpr int NTM = 8;                // 2048 / 256 row-tiles
  constexpr int TB  = 49152;            // A 32K + B 16K
  __shared__ __attribute__((aligned(16))) unsigned char lds[3 * TB];
  const int tid = threadIdx.x, wave = tid >> 6, lane = tid & 63;
  const int l15 = lane & 15, l4 = lane >> 4;
  const int wr = wave >> 2, wc = wave & 3;

  const int nwg = gridDim.x, bid = blockIdx.x;
  const int cpx = nwg >> 3;
  const int swz = (bid & 7) * cpx + (bid >> 3);
  const int bx = swz / NTM, by = swz - bx * NTM;  // by-fast
  const int bm = by * 256, bn = bx * 128;

  const int srow = lane >> 3;
  const int sck  = ((lane & 7) ^ srow) * 8;
  const u16* Abase = A + (size_t)(bm + srow) * K + sck;
  const u16* Wbase = W + (size_t)(bn + srow) * K + sck;

  // units 0..3: A rows u*64..+63 ; units 4..5: B rows (u-4)*64..+63
  auto stageU = [&](int tt, int b, int u) {
    if (u < 4) {
      const int rb = u * 64 + wave * 8;
      load_lds16(Abase + (size_t)rb * K + tt * 64, &lds[b * TB + rb * 128]);
    } else {
      const int rb = (u - 4) * 64 + wave * 8;
      load_lds16(Wbase + (size_t)rb * K + tt * 64,
                 &lds[b * TB + 32768 + rb * 128]);
    }
  };

  f32x4 acc[8][2];
#pragma unroll
  for (int i = 0; i < 8; ++i)
#pragma unroll
    for (int j = 0; j < 2; ++j) acc[i][j] = (f32x4)0.f;

#pragma unroll
  for (int u = 0; u < 6; ++u) stageU(0, 0, u);
#pragma unroll
  for (int u = 0; u < 6; ++u) stageU(1, 1, u);
  asm volatile("s_waitcnt vmcnt(6)" ::: "memory");
  SBAR0;
  __builtin_amdgcn_s_barrier();

  const int arow = wr * 128 + l15;     // + mi*16
  const int brow = wc * 32 + l15;      // + ni*16
  const int ckx  = l15 & 7;

  bf16x8 af[4][2], bf[2][2];

  int br = 0, bs = 2;
  for (int t = 0; t < NT; ++t) {
    const int b0 = br * TB;
    const bool st = (t + 2 < NT);
    // ---- ph0: read af[0..3] (8) + bf (4); stage units {0,1,4} of t+2
#pragma unroll
    for (int mi = 0; mi < 4; ++mi)
#pragma unroll
      for (int ks = 0; ks < 2; ++ks)
        af[mi][ks] = *(const bf16x8*)&lds[b0 + (arow + mi * 16) * 128 +
                                          (((ks * 4 + l4) ^ ckx) * 16)];
#pragma unroll
    for (int ni = 0; ni < 2; ++ni)
#pragma unroll
      for (int ks = 0; ks < 2; ++ks)
        bf[ni][ks] = *(const bf16x8*)&lds[b0 + 32768 + (brow + ni * 16) * 128 +
                                          (((ks * 4 + l4) ^ ckx) * 16)];
    if (st) { stageU(t + 2, bs, 0); stageU(t + 2, bs, 1); stageU(t + 2, bs, 4); }
    SBAR0; __builtin_amdgcn_s_barrier();
    asm volatile("s_waitcnt lgkmcnt(0)" ::: "memory");
    SBAR0;
    __builtin_amdgcn_s_setprio(1);
#pragma unroll
    for (int ks = 0; ks < 2; ++ks)
#pragma unroll
      for (int mi = 0; mi < 4; ++mi)
#pragma unroll
        for (int ni = 0; ni < 2; ++ni)
          acc[mi][ni] = __builtin_amdgcn_mfma_f32_16x16x32_bf16(af[mi][ks], bf[ni][ks], acc[mi][ni], 0, 0, 0);
    __builtin_amdgcn_s_setprio(0);
    SBAR0; __builtin_amdgcn_s_barrier();
    // ---- ph1: read af[4..7] (8, overwrite af); stage units {2,3,5} of t+2
#pragma unroll
    for (int mi = 0; mi < 4; ++mi)
#pragma unroll
      for (int ks = 0; ks < 2; ++ks)
        af[mi][ks] = *(const bf16x8*)&lds[b0 + (arow + (mi + 4) * 16) * 128 +
                                          (((ks * 4 + l4) ^ ckx) * 16)];
    if (st) { stageU(t + 2, bs, 2); stageU(t + 2, bs, 3); stageU(t + 2, bs, 5); }
    SBAR0; __builtin_amdgcn_s_barrier();
    asm volatile("s_waitcnt lgkmcnt(0)" ::: "memory");
    SBAR0;
    __builtin_amdgcn_s_setprio(1);
#pragma unroll
    for (int ks = 0; ks < 2; ++ks)
#pragma unroll
      for (int mi = 0; mi < 4; ++mi)
#pragma unroll
        for (int ni = 0; ni < 2; ++ni)
          acc[mi + 4][ni] = __builtin_amdgcn_mfma_f32_16x16x32_bf16(af[mi][ks], bf[ni][ks], acc[mi + 4][ni], 0, 0, 0);
    __builtin_amdgcn_s_setprio(0);
    if (t < NT - 1) {
      if (t < NT - 2) asm volatile("s_waitcnt vmcnt(6)" ::: "memory");
      else            asm volatile("s_waitcnt vmcnt(0)" ::: "memory");
      SBAR0;
      __builtin_amdgcn_s_barrier();
    }
    br = (br == 2) ? 0 : br + 1;
    bs = (bs == 2) ? 0 : bs + 1;
  }

#pragma unroll
  for (int ni = 0; ni < 2; ++ni) {
    const int col = bn + wc * 32 + ni * 16 + l15;
    const float bv = bias[col];
#pragma unroll
    for (int mi = 0; mi < 8; ++mi) {
#pragma unroll
      for (int r = 0; r < 4; ++r) {
        const int row = bm + wr * 128 + mi * 16 + l4 * 4 + r;
        const float v = acc[mi][ni][r] + bv;
        if (OUT_BF16) ((u16*)Cout)[(size_t)row * STRIDE + col] = f2bf(v);
        else          ((float*)Cout)[(size_t)row * STRIDE + col] = v;
      }
    }
  }
}

// ---------------------------------------------------------------------------
// Fused rotary + V-transpose (r11 version, LDS cos/sin table).
// ---------------------------------------------------------------------------
__global__ __launch_bounds__(256)
void rotary_fused(const u16* __restrict__ qkv,
                  u16* __restrict__ Qb, u16* __restrict__ Kb,
                  u16* __restrict__ Vt) {
  __shared__ u16 vt[64][136];
  __shared__ float2 cs_tab[64][32];
  const int s0 = blockIdx.x * 64, h = blockIdx.y;
  const int tid = threadIdx.x;

  for (int idx = tid; idx < 2048; idx += 256) {
    const int r = idx >> 5, j = idx & 31;
    const float invf = exp2f(-(float)j * (13.287712379549449f / 32.f));
    float sn, c;
    sincosf((float)(s0 + r) * invf, &sn, &c);
    cs_tab[r][j] = make_float2(c, sn);
  }
  for (int idx = tid; idx < 1024; idx += 256) {
    const int r = idx >> 4, ck = idx & 15;
    us8 v = *(const us8*)(qkv + (size_t)(s0 + r) * H3 + h * 384 + 256 + ck * 8);
    *(us8*)&vt[r][ck * 8] = v;
  }
  __syncthreads();

  for (int idx = tid; idx < 2048; idx += 256) {
    const int r  = idx >> 5;
    const int sub = idx & 31;
    const int tq = sub >> 4;           // 0 = q, 1 = k
    const int ck = sub & 15;
    const int s = s0 + r;
    const u16* base = qkv + (size_t)s * H3 + h * 384 + tq * 128;
    us8 v = *(const us8*)(base + ck * 8);
    us8 p = *(const us8*)(base + ((ck * 8) ^ 32));
    const int d0 = ck * 8;
    const float sign = ((d0 & 63) < 32) ? -1.f : 1.f;
    const float sc = tq ? 1.f : 0.12751721769218683f;  // log2(e)/sqrt(128)
    us8 o;
#pragma unroll
    for (int e = 0; e < 8; ++e) {
      const float2 cs = cs_tab[r][(d0 + e) & 31];
      o[e] = f2bf((bf2f(v[e]) * cs.x + sign * bf2f(p[e]) * cs.y) * sc);
    }
    *(us8*)((tq ? Kb : Qb) + ((size_t)h * S + s) * HD + d0) = o;
  }
  for (int idx = tid; idx < 1024; idx += 256) {
    const int d = idx >> 3, c8 = idx & 7;
    us8 o;
#pragma unroll
    for (int e = 0; e < 8; ++e) o[e] = vt[c8 * 8 + e][d];
    *(us8*)(Vt + ((size_t)h * HD + d) * S + s0 + c8 * 8) = o;
  }
}

// ---------------------------------------------------------------------------
// Flash attention (r16): causal, single-buffered K/V (40 KB, 4 blocks/CU),
// balanced XCD mapping, defer-max.
// ---------------------------------------------------------------------------
__global__ __launch_bounds__(256)
void attn(const u16* __restrict__ Qb, const u16* __restrict__ Kb,
          const u16* __restrict__ Vt, u16* __restrict__ ctx) {
  __shared__ __attribute__((aligned(16))) unsigned char sK[64 * 256];
  __shared__ __attribute__((aligned(16))) unsigned char sV[128 * 128];
  __shared__ __attribute__((aligned(16))) unsigned char sP[4][16 * 128];
  const int bid = blockIdx.x;
  const int ixd = bid >> 3;
  const int h   = (bid & 7) * 4 + (ixd & 3);
  const int p   = ixd >> 2;
  const int g   = p >> 3, a = p & 7;
  const int qb  = 8 * g + ((g & 1) ? 7 - a : a);
  const int tid = threadIdx.x, wave = tid >> 6, lane = tid & 63;
  const int l15 = lane & 15, l4 = lane >> 4;
  const int qw0 = qb * 64 + wave * 16;

  auto stage = [&](int it) {
    const int t0 = it * 64;
#pragma unroll
    for (int c = 0; c < 4; ++c) {
      const int rbase = c * 16 + wave * 4;
      const int rr = rbase + (lane >> 4);
      const int pp = lane & 15;
      load_lds16(Kb + ((size_t)h * S + t0 + rr) * HD + ((pp ^ (rr & 15)) * 8),
                 &sK[rbase * 256]);
    }
#pragma unroll
    for (int c = 0; c < 4; ++c) {
      const int rbase = c * 32 + wave * 8;
      const int rr = rbase + (lane >> 3);
      const int pp = lane & 7;
      load_lds16(Vt + ((size_t)h * HD + rr) * S + t0 + ((pp ^ (rr & 7)) * 8),
                 &sV[rbase * 128]);
    }
  };

  bf16x8 qf[4];
  {
    const u16* qrow = Qb + ((size_t)h * S + qw0 + l15) * HD;
#pragma unroll
    for (int ks = 0; ks < 4; ++ks)
      qf[ks] = *(const bf16x8*)(qrow + ks * 32 + l4 * 8);
  }

  f32x4 of[8];
#pragma unroll
  for (int i = 0; i < 8; ++i) of[i] = (f32x4)0.f;
  float mrun[4] = {-1e30f, -1e30f, -1e30f, -1e30f};
  float lrun[4] = {0.f, 0.f, 0.f, 0.f};

  const int nt = qb + 1;
  stage(0);
  for (int it = 0; it < nt; ++it) {
    const int t0 = it * 64;
    asm volatile("s_waitcnt vmcnt(0)" ::: "memory");
    SBAR0;
    __builtin_amdgcn_s_barrier();
    SBAR0;

    f32x4 sc[4];
#pragma unroll
    for (int nf = 0; nf < 4; ++nf) sc[nf] = (f32x4)0.f;
#pragma unroll
    for (int nf = 0; nf < 4; ++nf) {
      const int trow = nf * 16 + l15;
#pragma unroll
      for (int ks = 0; ks < 4; ++ks) {
        const int chunk = ks * 4 + l4;
        bf16x8 kf = *(const bf16x8*)&sK[trow * 256 + ((chunk ^ (trow & 15)) * 16)];
        sc[nf] = __builtin_amdgcn_mfma_f32_16x16x32_bf16(qf[ks], kf, sc[nf], 0, 0, 0);
      }
    }

    if (it == qb) {
#pragma unroll
      for (int nf = 0; nf < 4; ++nf) {
        const int tg = t0 + nf * 16 + l15;
#pragma unroll
        for (int r = 0; r < 4; ++r) {
          const int sg = qw0 + l4 * 4 + r;
          if (tg > sg) sc[nf][r] = -1e30f;
        }
      }
    }

    f32x4 vm = sc[0];
#pragma unroll
    for (int nf = 1; nf < 4; ++nf)
#pragma unroll
      for (int r = 0; r < 4; ++r) vm[r] = fmaxf(vm[r], sc[nf][r]);
#pragma unroll
    for (int m = 1; m <= 8; m <<= 1)
#pragma unroll
      for (int r = 0; r < 4; ++r) vm[r] = fmaxf(vm[r], __shfl_xor(vm[r], m, 64));

    bool need = false;
#pragma unroll
    for (int r = 0; r < 4; ++r) need = need || (vm[r] > mrun[r] + 8.f);
    if (__builtin_amdgcn_ballot_w64(need)) {
#pragma unroll
      for (int r = 0; r < 4; ++r) {
        const float nm = fmaxf(mrun[r], vm[r]);
        const float scale = exp2f(mrun[r] - nm);
        mrun[r] = nm;
        lrun[r] *= scale;
#pragma unroll
        for (int i = 0; i < 8; ++i) of[i][r] *= scale;
      }
    }

    f32x4 rs = (f32x4)0.f;
#pragma unroll
    for (int nf = 0; nf < 4; ++nf) {
#pragma unroll
      for (int r = 0; r < 4; ++r) {
        const float pv = exp2f(sc[nf][r] - mrun[r]);
        rs[r] += pv;
        const int row = l4 * 4 + r;
        const int t = nf * 16 + l15;
        const int chunk = t >> 3;
        *(u16*)&sP[wave][row * 128 + ((chunk ^ (row & 7)) * 16) + (t & 7) * 2] = f2bf(pv);
      }
    }
#pragma unroll
    for (int m = 1; m <= 8; m <<= 1)
#pragma unroll
      for (int r = 0; r < 4; ++r) rs[r] += __shfl_xor(rs[r], m, 64);
#pragma unroll
    for (int r = 0; r < 4; ++r) lrun[r] += rs[r];

    asm volatile("s_waitcnt lgkmcnt(0)" ::: "memory");
    SBAR0;

    bf16x8 pa[2];
#pragma unroll
    for (int ksP = 0; ksP < 2; ++ksP) {
      const int chunk = ksP * 4 + l4;
      pa[ksP] = *(const bf16x8*)&sP[wave][l15 * 128 + ((chunk ^ (l15 & 7)) * 16)];
    }
#pragma unroll
    for (int nf2 = 0; nf2 < 8; ++nf2) {
      const int d = nf2 * 16 + l15;
#pragma unroll
      for (int ksP = 0; ksP < 2; ++ksP) {
        const int chunk = ksP * 4 + l4;
        bf16x8 vf = *(const bf16x8*)&sV[d * 128 + ((chunk ^ (d & 7)) * 16)];
        of[nf2] = __builtin_amdgcn_mfma_f32_16x16x32_bf16(pa[ksP], vf, of[nf2], 0, 0, 0);
      }
    }
    SBAR0;
    __builtin_amdgcn_s_barrier();
    if (it + 1 < nt) stage(it + 1);
  }

  float invr[4];
#pragma unroll
  for (int r = 0; r < 4; ++r) invr[r] = 1.f / lrun[r];
#pragma unroll
  for (int nf2 = 0; nf2 < 8; ++nf2) {
    const int d = nf2 * 16 + l15;
#pragma unroll
    for (int r = 0; r < 4; ++r) {
      const int srow = qw0 + l4 * 4 + r;
      ctx[(size_t)srow * H + h * HD + d] = f2bf(of[nf2][r] * invr[r]);
    }
  }
}

// ---------------------------------------------------------------------------
extern "C" void kernel_launch(void* const* d_in, const int* in_sizes, int n_in,
                              void* d_out, int out_size, void* d_ws, size_t ws_size,
                              hipStream_t stream) {
  (void)in_sizes; (void)n_in; (void)out_size; (void)ws_size;
  const float* hidden  = (const float*)d_in[0];
  const float* w_qkv   = (const float*)d_in[4];
  const float* b_qkv   = (const float*)d_in[5];
  const float* w_dense = (const float*)d_in[6];
  const float* b_dense = (const float*)d_in[7];
  float* out = (float*)d_out;

  char* ws = (char*)d_ws;
  u16* wqkvb   = (u16*)(ws + 0);                       // 100.66 MB (0..100663296)
  u16* ctxb    = (u16*)(ws + 41943040);                // 16.78 MB (after QKV; wqkvb dead)
  u16* hb      = (u16*)(ws + 100663296);               // 16.78 MB
  u16* qkvb    = (u16*)(ws + 117440512);               // 50.33 MB
  u16* Qbp     = (u16*)(ws + 167772160);               // 16.78 MB
  u16* Kbp     = (u16*)(ws + 184549376);               // 16.78 MB
  u16* Vtp     = (u16*)(ws + 201326592);               // 16.78 MB
  u16* wdenseb = (u16*)(ws + 218103808);               // 33.55 MB, ends 251.7 MB

  cast_all<<<2048, 256, 0, stream>>>(w_qkv, hidden, w_dense, wqkvb, hb, wdenseb);
  // QKV hybrid split, both chunks exactly 256 blocks:
  //   cols 0..8191:     gemm256  (256x256) -> 8 x 32 = 256 blocks
  //   cols 8192..12287: gemm256n (256x128) -> 8 x 32 = 256 blocks
  gemm256<H3, 1><<<dim3(256), 512, 0, stream>>>(hb, wqkvb, b_qkv, qkvb);
  gemm256n<H3, 1><<<dim3(256), 512, 0, stream>>>(
      hb, wqkvb + (size_t)8192 * 4096, b_qkv + 8192, (u16*)qkvb + 8192);
  rotary_fused<<<dim3(S / 64, NH), 256, 0, stream>>>(qkvb, Qbp, Kbp, Vtp);
  // attn: single-buffer 40KB (4 blocks/CU), balanced XCD mapping, defer-max
  attn<<<dim3(1024), 256, 0, stream>>>(Qbp, Kbp, Vtp, ctxb);
  // dense: gemm256n (256x128) -> 8 x 32 = 256 blocks = 1/CU exact
  gemm256n<H, 0><<<dim3(256), 512, 0, stream>>>(ctxb, wdenseb, b_dense, out);
}

// Round 18
// 444.283 us; speedup vs baseline: 1.0175x; 1.0175x over previous
//
#include <hip/hip_runtime.h>
#include <math.h>
#include <stdint.h>

constexpr int S  = 2048;
constexpr int H  = 4096;
constexpr int NH = 32;
constexpr int HD = 128;
constexpr int H3 = 3 * H;   // 12288

typedef unsigned short u16;
typedef __bf16 bf16x8 __attribute__((ext_vector_type(8)));
typedef float  f32x4  __attribute__((ext_vector_type(4)));
typedef unsigned short us8 __attribute__((ext_vector_type(8)));

// f32 -> bf16 (RNE) as raw u16
__device__ __forceinline__ u16 f2bf(float f) {
  uint32_t u = __float_as_uint(f);
  uint32_t r = (u + 0x7fff + ((u >> 16) & 1)) >> 16;
  return (u16)r;
}
__device__ __forceinline__ float bf2f(u16 u) {
  return __uint_as_float((uint32_t)u << 16);
}

// async global->LDS, 16B per lane. LDS dest = wave-uniform base + lane*16.
__device__ __forceinline__ void load_lds16(const void* g, void* l) {
  __builtin_amdgcn_global_load_lds(
      (__attribute__((address_space(1))) void*)(uintptr_t)g,
      (__attribute__((address_space(3))) void*)l,
      16, 0, 0);
}

#define SBAR0 __builtin_amdgcn_sched_barrier(0)

// ---------------------------------------------------------------------------
// Fused cast: w_qkv, hidden, w_dense f32 -> bf16 in ONE launch (grid-stride).
// ---------------------------------------------------------------------------
__global__ __launch_bounds__(256)
void cast_all(const float* __restrict__ w_qkv, const float* __restrict__ hidden,
              const float* __restrict__ w_dense, u16* __restrict__ wq,
              u16* __restrict__ hb, u16* __restrict__ wd) {
  constexpr int NQ  = H3 * H / 4;          // 12582912
  constexpr int NHd = S * H / 4;           // 2097152
  constexpr int ND  = H * H / 4;           // 4194304
  constexpr int NT  = NQ + NHd + ND;
  for (int i = blockIdx.x * 256 + threadIdx.x; i < NT; i += gridDim.x * 256) {
    const float4* src;
    ushort4* dst;
    int j = i;
    if (j < NQ)            { src = (const float4*)w_qkv;  dst = (ushort4*)wq; }
    else if (j < NQ + NHd) { j -= NQ; src = (const float4*)hidden; dst = (ushort4*)hb; }
    else                   { j -= NQ + NHd; src = (const float4*)w_dense; dst = (ushort4*)wd; }
    float4 v = src[j];
    ushort4 o;
    o.x = f2bf(v.x); o.y = f2bf(v.y); o.z = f2bf(v.z); o.w = f2bf(v.w);
    dst[j] = o;
  }
}

// ---------------------------------------------------------------------------
// m201-geometry GEMM (chunk A, measured 132us / 44.9% MfmaUtil): BM=BN=256,
// BK=64; 512 thr = 8 waves (2M x 4N), per-wave 128x64 (acc[8][4]). 2 LDS
// buffers (128 KiB), region-tracked staging into the buffer being read,
// vmcnt(8) boundary. STRIDE = output row stride.
// ---------------------------------------------------------------------------
template<int STRIDE, int OUT_BF16>
__global__ __launch_bounds__(512, 2)
void gemm256(const u16* __restrict__ A, const u16* __restrict__ W,
             const float* __restrict__ bias, void* __restrict__ Cout) {
  constexpr int K   = 4096;
  constexpr int NT  = K / 64;           // 64 K-tiles
  constexpr int NTM = 8;                // 2048 / 256 row-tiles
  constexpr int TB  = 65536;            // per-buffer: A 32K + B 32K
  __shared__ __attribute__((aligned(16))) unsigned char lds[2 * TB];
  const int tid = threadIdx.x, wave = tid >> 6, lane = tid & 63;
  const int l15 = lane & 15, l4 = lane >> 4;
  const int wr = wave >> 2, wc = wave & 3;

  const int nwg = gridDim.x, bid = blockIdx.x;
  const int cpx = nwg >> 3;
  const int swz = (bid & 7) * cpx + (bid >> 3);
  const int bx = swz / NTM, by = swz - bx * NTM;  // by-fast (column-major)
  const int bm = by * 256, bn = bx * 256;

  const int srow = lane >> 3;                     // 0..7
  const int sck  = ((lane & 7) ^ srow) * 8;       // inverse-swizzled source
  const u16* Abase = A + (size_t)(bm + srow) * K + sck;
  const u16* Wbase = W + (size_t)(bn + srow) * K + sck;

  auto stageU = [&](int tt, int u) {
    const int b = tt & 1;
    if (u < 4) {
      const int rb = u * 64 + wave * 8;
      load_lds16(Abase + (size_t)rb * K + tt * 64, &lds[b * TB + rb * 128]);
    } else {
      const int rb = (u - 4) * 64 + wave * 8;
      load_lds16(Wbase + (size_t)rb * K + tt * 64,
                 &lds[b * TB + 32768 + rb * 128]);
    }
  };

  f32x4 acc[8][4];
#pragma unroll
  for (int i = 0; i < 8; ++i)
#pragma unroll
    for (int j = 0; j < 4; ++j) acc[i][j] = (f32x4)0.f;

#pragma unroll
  for (int u = 0; u < 8; ++u) stageU(0, u);
#pragma unroll
  for (int u = 0; u < 8; ++u) stageU(1, u);
  asm volatile("s_waitcnt vmcnt(8)" ::: "memory");
  SBAR0;
  __builtin_amdgcn_s_barrier();

  const int arow = wr * 128 + l15;     // + mi*16
  const int brow = wc * 64 + l15;      // + ni*16
  const int ckx  = l15 & 7;

  bf16x8 af[4][2], bfA[2][2], bfB[2][2];

  for (int t = 0; t < NT; ++t) {
    const int b0 = (t & 1) * TB;
    const bool st = (t + 2 < NT);
    // ---- ph0: read af[0..3] (8) + bfA (4); no stage
#pragma unroll
    for (int mi = 0; mi < 4; ++mi)
#pragma unroll
      for (int ks = 0; ks < 2; ++ks)
        af[mi][ks] = *(const bf16x8*)&lds[b0 + (arow + mi * 16) * 128 +
                                          (((ks * 4 + l4) ^ ckx) * 16)];
#pragma unroll
    for (int ni = 0; ni < 2; ++ni)
#pragma unroll
      for (int ks = 0; ks < 2; ++ks)
        bfA[ni][ks] = *(const bf16x8*)&lds[b0 + 32768 + (brow + ni * 16) * 128 +
                                           (((ks * 4 + l4) ^ ckx) * 16)];
    SBAR0; __builtin_amdgcn_s_barrier();
    asm volatile("s_waitcnt lgkmcnt(0)" ::: "memory");
    SBAR0;
    __builtin_amdgcn_s_setprio(1);
#pragma unroll
    for (int ks = 0; ks < 2; ++ks)
#pragma unroll
      for (int mi = 0; mi < 4; ++mi)
#pragma unroll
        for (int ni = 0; ni < 2; ++ni)
          acc[mi][ni] = __builtin_amdgcn_mfma_f32_16x16x32_bf16(af[mi][ks], bfA[ni][ks], acc[mi][ni], 0, 0, 0);
    __builtin_amdgcn_s_setprio(0);
    SBAR0; __builtin_amdgcn_s_barrier();
    // ---- ph1: read bfB (4); stage A rows {0-63, 128-191} of t+2
#pragma unroll
    for (int ni = 0; ni < 2; ++ni)
#pragma unroll
      for (int ks = 0; ks < 2; ++ks)
        bfB[ni][ks] = *(const bf16x8*)&lds[b0 + 32768 + (brow + (ni + 2) * 16) * 128 +
                                           (((ks * 4 + l4) ^ ckx) * 16)];
    if (st) { stageU(t + 2, 0); stageU(t + 2, 2); }
    SBAR0; __builtin_amdgcn_s_barrier();
    asm volatile("s_waitcnt lgkmcnt(0)" ::: "memory");
    SBAR0;
    __builtin_amdgcn_s_setprio(1);
#pragma unroll
    for (int ks = 0; ks < 2; ++ks)
#pragma unroll
      for (int mi = 0; mi < 4; ++mi)
#pragma unroll
        for (int ni = 0; ni < 2; ++ni)
          acc[mi][ni + 2] = __builtin_amdgcn_mfma_f32_16x16x32_bf16(af[mi][ks], bfB[ni][ks], acc[mi][ni + 2], 0, 0, 0);
    __builtin_amdgcn_s_setprio(0);
    SBAR0; __builtin_amdgcn_s_barrier();
    // ---- ph2: read af[4..7] (8, overwrite af); stage B rows 0-127 of t+2
#pragma unroll
    for (int mi = 0; mi < 4; ++mi)
#pragma unroll
      for (int ks = 0; ks < 2; ++ks)
        af[mi][ks] = *(const bf16x8*)&lds[b0 + (arow + (mi + 4) * 16) * 128 +
                                          (((ks * 4 + l4) ^ ckx) * 16)];
    if (st) { stageU(t + 2, 4); stageU(t + 2, 5); }
    SBAR0; __builtin_amdgcn_s_barrier();
    asm volatile("s_waitcnt lgkmcnt(0)" ::: "memory");
    SBAR0;
    __builtin_amdgcn_s_setprio(1);
#pragma unroll
    for (int ks = 0; ks < 2; ++ks)
#pragma unroll
      for (int mi = 0; mi < 4; ++mi)
#pragma unroll
        for (int ni = 0; ni < 2; ++ni)
          acc[mi + 4][ni] = __builtin_amdgcn_mfma_f32_16x16x32_bf16(af[mi][ks], bfA[ni][ks], acc[mi + 4][ni], 0, 0, 0);
    __builtin_amdgcn_s_setprio(0);
    SBAR0; __builtin_amdgcn_s_barrier();
    // ---- ph3: no reads; stage A {64-127,192-255} + B {128-255}; MFMA
    if (st) { stageU(t + 2, 1); stageU(t + 2, 3); stageU(t + 2, 6); stageU(t + 2, 7); }
    SBAR0;
    __builtin_amdgcn_s_setprio(1);
#pragma unroll
    for (int ks = 0; ks < 2; ++ks)
#pragma unroll
      for (int mi = 0; mi < 4; ++mi)
#pragma unroll
        for (int ni = 0; ni < 2; ++ni)
          acc[mi + 4][ni + 2] = __builtin_amdgcn_mfma_f32_16x16x32_bf16(af[mi][ks], bfB[ni][ks], acc[mi + 4][ni + 2], 0, 0, 0);
    __builtin_amdgcn_s_setprio(0);
    if (t < NT - 2)       asm volatile("s_waitcnt vmcnt(8)" ::: "memory");
    else if (t == NT - 2) asm volatile("s_waitcnt vmcnt(0)" ::: "memory");
    SBAR0;
    if (t < NT - 1) __builtin_amdgcn_s_barrier();
  }

#pragma unroll
  for (int ni = 0; ni < 4; ++ni) {
    const int col = bn + wc * 64 + ni * 16 + l15;
    const float bv = bias[col];
#pragma unroll
    for (int mi = 0; mi < 8; ++mi) {
#pragma unroll
      for (int r = 0; r < 4; ++r) {
        const int row = bm + wr * 128 + mi * 16 + l4 * 4 + r;
        const float v = acc[mi][ni][r] + bv;
        if (OUT_BF16) ((u16*)Cout)[(size_t)row * STRIDE + col] = f2bf(v);
        else          ((float*)Cout)[(size_t)row * STRIDE + col] = v;
      }
    }
  }
}

// ---------------------------------------------------------------------------
// 4-phase GEMM (r8, 929 TF measured): BM=128, BN=256, BK=64; 512 thr;
// 3 LDS bufs; counted vmcnt(6). STRIDE = output row stride.
// ---------------------------------------------------------------------------
template<int STRIDE, int OUT_BF16>
__global__ __launch_bounds__(512, 2)
void gemm8p(const u16* __restrict__ A, const u16* __restrict__ W,
            const float* __restrict__ bias, void* __restrict__ Cout) {
  constexpr int K  = 4096;
  constexpr int NT = K / 64;
  constexpr int NTM = 16;
  constexpr int TB = 49152;
  __shared__ __attribute__((aligned(16))) unsigned char lds[3 * TB];
  const int tid = threadIdx.x, wave = tid >> 6, lane = tid & 63;
  const int l15 = lane & 15, l4 = lane >> 4;
  const int wr = wave >> 2, wc = wave & 3;

  const int nwg = gridDim.x, bid = blockIdx.x;
  const int cpx = nwg >> 3;
  const int swz = (bid & 7) * cpx + (bid >> 3);
  const int bx = swz / NTM, by = swz - bx * NTM;  // by-fast (column-major)
  const int bm = by * 128, bn = bx * 256;

  const int srow = lane >> 3;
  const int sck  = ((lane & 7) ^ srow) * 8;
  const u16* Abase = A + (size_t)(bm + srow) * K + sck;
  const u16* Wbase = W + (size_t)(bn + srow) * K + sck;

  auto stageA = [&](int tt, int b) {
#pragma unroll
    for (int j = 0; j < 2; ++j) {
      const int rb = j * 64 + wave * 8;
      load_lds16(Abase + (size_t)rb * K + tt * 64, &lds[b * TB + rb * 128]);
    }
  };
  auto stageB = [&](int tt, int b, int u) {
#pragma unroll
    for (int j = 0; j < 2; ++j) {
      const int rb = u * 128 + j * 64 + wave * 8;
      load_lds16(Wbase + (size_t)rb * K + tt * 64,
                 &lds[b * TB + 16384 + rb * 128]);
    }
  };

  f32x4 acc[4][4];
#pragma unroll
  for (int i = 0; i < 4; ++i)
#pragma unroll
    for (int j = 0; j < 4; ++j) acc[i][j] = (f32x4)0.f;

  stageA(0, 0); stageB(0, 0, 0); stageB(0, 0, 1);
  stageA(1, 1); stageB(1, 1, 0); stageB(1, 1, 1);
  asm volatile("s_waitcnt vmcnt(6)" ::: "memory");
  SBAR0;
  __builtin_amdgcn_s_barrier();

  const int arow = wr * 64 + l15;
  const int brow = wc * 64 + l15;
  const int ckx  = l15 & 7;

  bf16x8 af[4][2], bf[4][2];

  int br = 0, bs = 2;
  for (int t = 0; t < NT; ++t) {
    const int b0 = br * TB;
#pragma unroll
    for (int mi = 0; mi < 2; ++mi)
#pragma unroll
      for (int ks = 0; ks < 2; ++ks)
        af[mi][ks] = *(const bf16x8*)&lds[b0 + (arow + mi * 16) * 128 +
                                          (((ks * 4 + l4) ^ ckx) * 16)];
#pragma unroll
    for (int ni = 0; ni < 2; ++ni)
#pragma unroll
      for (int ks = 0; ks < 2; ++ks)
        bf[ni][ks] = *(const bf16x8*)&lds[b0 + 16384 + (brow + ni * 16) * 128 +
                                          (((ks * 4 + l4) ^ ckx) * 16)];
    if (t < NT - 2) stageA(t + 2, bs);
    SBAR0; __builtin_amdgcn_s_barrier();
    asm volatile("s_waitcnt lgkmcnt(0)" ::: "memory");
    SBAR0;
    __builtin_amdgcn_s_setprio(1);
#pragma unroll
    for (int ks = 0; ks < 2; ++ks)
#pragma unroll
      for (int mi = 0; mi < 2; ++mi)
#pragma unroll
        for (int ni = 0; ni < 2; ++ni)
          acc[mi][ni] = __builtin_amdgcn_mfma_f32_16x16x32_bf16(af[mi][ks], bf[ni][ks], acc[mi][ni], 0, 0, 0);
    __builtin_amdgcn_s_setprio(0);
    SBAR0; __builtin_amdgcn_s_barrier();
#pragma unroll
    for (int ni = 2; ni < 4; ++ni)
#pragma unroll
      for (int ks = 0; ks < 2; ++ks)
        bf[ni][ks] = *(const bf16x8*)&lds[b0 + 16384 + (brow + ni * 16) * 128 +
                                          (((ks * 4 + l4) ^ ckx) * 16)];
    if (t < NT - 2) stageB(t + 2, bs, 0);
    SBAR0; __builtin_amdgcn_s_barrier();
    asm volatile("s_waitcnt lgkmcnt(0)" ::: "memory");
    SBAR0;
    __builtin_amdgcn_s_setprio(1);
#pragma unroll
    for (int ks = 0; ks < 2; ++ks)
#pragma unroll
      for (int mi = 0; mi < 2; ++mi)
#pragma unroll
        for (int ni = 2; ni < 4; ++ni)
          acc[mi][ni] = __builtin_amdgcn_mfma_f32_16x16x32_bf16(af[mi][ks], bf[ni][ks], acc[mi][ni], 0, 0, 0);
    __builtin_amdgcn_s_setprio(0);
    SBAR0; __builtin_amdgcn_s_barrier();
#pragma unroll
    for (int mi = 2; mi < 4; ++mi)
#pragma unroll
      for (int ks = 0; ks < 2; ++ks)
        af[mi][ks] = *(const bf16x8*)&lds[b0 + (arow + mi * 16) * 128 +
                                          (((ks * 4 + l4) ^ ckx) * 16)];
    if (t < NT - 2) stageB(t + 2, bs, 1);
    SBAR0; __builtin_amdgcn_s_barrier();
    asm volatile("s_waitcnt lgkmcnt(0)" ::: "memory");
    SBAR0;
    __builtin_amdgcn_s_setprio(1);
#pragma unroll
    for (int ks = 0; ks < 2; ++ks)
#pragma unroll
      for (int mi = 2; mi < 4; ++mi)
#pragma unroll
        for (int ni = 0; ni < 2; ++ni)
          acc[mi][ni] = __builtin_amdgcn_mfma_f32_16x16x32_bf16(af[mi][ks], bf[ni][ks], acc[mi][ni], 0, 0, 0);
    __builtin_amdgcn_s_setprio(0);
    SBAR0; __builtin_amdgcn_s_barrier();
    __builtin_amdgcn_s_setprio(1);
#pragma unroll
    for (int ks = 0; ks < 2; ++ks)
#pragma unroll
      for (int mi = 2; mi < 4; ++mi)
#pragma unroll
        for (int ni = 2; ni < 4; ++ni)
          acc[mi][ni] = __builtin_amdgcn_mfma_f32_16x16x32_bf16(af[mi][ks], bf[ni][ks], acc[mi][ni], 0, 0, 0);
    __builtin_amdgcn_s_setprio(0);
    if (t < NT - 1) {
      if (t < NT - 2) asm volatile("s_waitcnt vmcnt(6)" ::: "memory");
      else            asm volatile("s_waitcnt vmcnt(0)" ::: "memory");
      SBAR0;
      __builtin_amdgcn_s_barrier();
    }
    br = (br == 2) ? 0 : br + 1;
    bs = (bs == 2) ? 0 : bs + 1;
  }

#pragma unroll
  for (int ni = 0; ni < 4; ++ni) {
    const int col = bn + wc * 64 + ni * 16 + l15;
    const float bv = bias[col];
#pragma unroll
    for (int mi = 0; mi < 4; ++mi) {
#pragma unroll
      for (int r = 0; r < 4; ++r) {
        const int row = bm + wr * 64 + mi * 16 + l4 * 4 + r;
        const float v = acc[mi][ni][r] + bv;
        if (OUT_BF16) ((u16*)Cout)[(size_t)row * STRIDE + col] = f2bf(v);
        else          ((float*)Cout)[(size_t)row * STRIDE + col] = v;
      }
    }
  }
}

// ---------------------------------------------------------------------------
// Fused rotary + V-transpose (r11 version, LDS cos/sin table).
// ---------------------------------------------------------------------------
__global__ __launch_bounds__(256)
void rotary_fused(const u16* __restrict__ qkv,
                  u16* __restrict__ Qb, u16* __restrict__ Kb,
                  u16* __restrict__ Vt) {
  __shared__ u16 vt[64][136];
  __shared__ float2 cs_tab[64][32];
  const int s0 = blockIdx.x * 64, h = blockIdx.y;
  const int tid = threadIdx.x;

  for (int idx = tid; idx < 2048; idx += 256) {
    const int r = idx >> 5, j = idx & 31;
    const float invf = exp2f(-(float)j * (13.287712379549449f / 32.f));
    float sn, c;
    sincosf((float)(s0 + r) * invf, &sn, &c);
    cs_tab[r][j] = make_float2(c, sn);
  }
  for (int idx = tid; idx < 1024; idx += 256) {
    const int r = idx >> 4, ck = idx & 15;
    us8 v = *(const us8*)(qkv + (size_t)(s0 + r) * H3 + h * 384 + 256 + ck * 8);
    *(us8*)&vt[r][ck * 8] = v;
  }
  __syncthreads();

  for (int idx = tid; idx < 2048; idx += 256) {
    const int r  = idx >> 5;
    const int sub = idx & 31;
    const int tq = sub >> 4;           // 0 = q, 1 = k
    const int ck = sub & 15;
    const int s = s0 + r;
    const u16* base = qkv + (size_t)s * H3 + h * 384 + tq * 128;
    us8 v = *(const us8*)(base + ck * 8);
    us8 p = *(const us8*)(base + ((ck * 8) ^ 32));
    const int d0 = ck * 8;
    const float sign = ((d0 & 63) < 32) ? -1.f : 1.f;
    const float sc = tq ? 1.f : 0.12751721769218683f;  // log2(e)/sqrt(128)
    us8 o;
#pragma unroll
    for (int e = 0; e < 8; ++e) {
      const float2 cs = cs_tab[r][(d0 + e) & 31];
      o[e] = f2bf((bf2f(v[e]) * cs.x + sign * bf2f(p[e]) * cs.y) * sc);
    }
    *(us8*)((tq ? Kb : Qb) + ((size_t)h * S + s) * HD + d0) = o;
  }
  for (int idx = tid; idx < 1024; idx += 256) {
    const int d = idx >> 3, c8 = idx & 7;
    us8 o;
#pragma unroll
    for (int e = 0; e < 8; ++e) o[e] = vt[c8 * 8 + e][d];
    *(us8*)(Vt + ((size_t)h * HD + d) * S + s0 + c8 * 8) = o;
  }
}

// ---------------------------------------------------------------------------
// Flash attention (r16-measured-best): causal, single-buffered K/V (40 KB,
// 4 blocks/CU), balanced XCD mapping, defer-max.
// ---------------------------------------------------------------------------
__global__ __launch_bounds__(256)
void attn(const u16* __restrict__ Qb, const u16* __restrict__ Kb,
          const u16* __restrict__ Vt, u16* __restrict__ ctx) {
  __shared__ __attribute__((aligned(16))) unsigned char sK[64 * 256];
  __shared__ __attribute__((aligned(16))) unsigned char sV[128 * 128];
  __shared__ __attribute__((aligned(16))) unsigned char sP[4][16 * 128];
  const int bid = blockIdx.x;
  const int ixd = bid >> 3;
  const int h   = (bid & 7) * 4 + (ixd & 3);
  const int p   = ixd >> 2;
  const int g   = p >> 3, a = p & 7;
  const int qb  = 8 * g + ((g & 1) ? 7 - a : a);
  const int tid = threadIdx.x, wave = tid >> 6, lane = tid & 63;
  const int l15 = lane & 15, l4 = lane >> 4;
  const int qw0 = qb * 64 + wave * 16;

  auto stage = [&](int it) {
    const int t0 = it * 64;
#pragma unroll
    for (int c = 0; c < 4; ++c) {
      const int rbase = c * 16 + wave * 4;
      const int rr = rbase + (lane >> 4);
      const int pp = lane & 15;
      load_lds16(Kb + ((size_t)h * S + t0 + rr) * HD + ((pp ^ (rr & 15)) * 8),
                 &sK[rbase * 256]);
    }
#pragma unroll
    for (int c = 0; c < 4; ++c) {
      const int rbase = c * 32 + wave * 8;
      const int rr = rbase + (lane >> 3);
      const int pp = lane & 7;
      load_lds16(Vt + ((size_t)h * HD + rr) * S + t0 + ((pp ^ (rr & 7)) * 8),
                 &sV[rbase * 128]);
    }
  };

  bf16x8 qf[4];
  {
    const u16* qrow = Qb + ((size_t)h * S + qw0 + l15) * HD;
#pragma unroll
    for (int ks = 0; ks < 4; ++ks)
      qf[ks] = *(const bf16x8*)(qrow + ks * 32 + l4 * 8);
  }

  f32x4 of[8];
#pragma unroll
  for (int i = 0; i < 8; ++i) of[i] = (f32x4)0.f;
  float mrun[4] = {-1e30f, -1e30f, -1e30f, -1e30f};
  float lrun[4] = {0.f, 0.f, 0.f, 0.f};

  const int nt = qb + 1;
  stage(0);
  for (int it = 0; it < nt; ++it) {
    const int t0 = it * 64;
    asm volatile("s_waitcnt vmcnt(0)" ::: "memory");
    SBAR0;
    __builtin_amdgcn_s_barrier();
    SBAR0;

    f32x4 sc[4];
#pragma unroll
    for (int nf = 0; nf < 4; ++nf) sc[nf] = (f32x4)0.f;
#pragma unroll
    for (int nf = 0; nf < 4; ++nf) {
      const int trow = nf * 16 + l15;
#pragma unroll
      for (int ks = 0; ks < 4; ++ks) {
        const int chunk = ks * 4 + l4;
        bf16x8 kf = *(const bf16x8*)&sK[trow * 256 + ((chunk ^ (trow & 15)) * 16)];
        sc[nf] = __builtin_amdgcn_mfma_f32_16x16x32_bf16(qf[ks], kf, sc[nf], 0, 0, 0);
      }
    }

    if (it == qb) {
#pragma unroll
      for (int nf = 0; nf < 4; ++nf) {
        const int tg = t0 + nf * 16 + l15;
#pragma unroll
        for (int r = 0; r < 4; ++r) {
          const int sg = qw0 + l4 * 4 + r;
          if (tg > sg) sc[nf][r] = -1e30f;
        }
      }
    }

    f32x4 vm = sc[0];
#pragma unroll
    for (int nf = 1; nf < 4; ++nf)
#pragma unroll
      for (int r = 0; r < 4; ++r) vm[r] = fmaxf(vm[r], sc[nf][r]);
#pragma unroll
    for (int m = 1; m <= 8; m <<= 1)
#pragma unroll
      for (int r = 0; r < 4; ++r) vm[r] = fmaxf(vm[r], __shfl_xor(vm[r], m, 64));

    bool need = false;
#pragma unroll
    for (int r = 0; r < 4; ++r) need = need || (vm[r] > mrun[r] + 8.f);
    if (__builtin_amdgcn_ballot_w64(need)) {
#pragma unroll
      for (int r = 0; r < 4; ++r) {
        const float nm = fmaxf(mrun[r], vm[r]);
        const float scale = exp2f(mrun[r] - nm);
        mrun[r] = nm;
        lrun[r] *= scale;
#pragma unroll
        for (int i = 0; i < 8; ++i) of[i][r] *= scale;
      }
    }

    f32x4 rs = (f32x4)0.f;
#pragma unroll
    for (int nf = 0; nf < 4; ++nf) {
#pragma unroll
      for (int r = 0; r < 4; ++r) {
        const float pv = exp2f(sc[nf][r] - mrun[r]);
        rs[r] += pv;
        const int row = l4 * 4 + r;
        const int t = nf * 16 + l15;
        const int chunk = t >> 3;
        *(u16*)&sP[wave][row * 128 + ((chunk ^ (row & 7)) * 16) + (t & 7) * 2] = f2bf(pv);
      }
    }
#pragma unroll
    for (int m = 1; m <= 8; m <<= 1)
#pragma unroll
      for (int r = 0; r < 4; ++r) rs[r] += __shfl_xor(rs[r], m, 64);
#pragma unroll
    for (int r = 0; r < 4; ++r) lrun[r] += rs[r];

    asm volatile("s_waitcnt lgkmcnt(0)" ::: "memory");
    SBAR0;

    bf16x8 pa[2];
#pragma unroll
    for (int ksP = 0; ksP < 2; ++ksP) {
      const int chunk = ksP * 4 + l4;
      pa[ksP] = *(const bf16x8*)&sP[wave][l15 * 128 + ((chunk ^ (l15 & 7)) * 16)];
    }
#pragma unroll
    for (int nf2 = 0; nf2 < 8; ++nf2) {
      const int d = nf2 * 16 + l15;
#pragma unroll
      for (int ksP = 0; ksP < 2; ++ksP) {
        const int chunk = ksP * 4 + l4;
        bf16x8 vf = *(const bf16x8*)&sV[d * 128 + ((chunk ^ (d & 7)) * 16)];
        of[nf2] = __builtin_amdgcn_mfma_f32_16x16x32_bf16(pa[ksP], vf, of[nf2], 0, 0, 0);
      }
    }
    SBAR0;
    __builtin_amdgcn_s_barrier();
    if (it + 1 < nt) stage(it + 1);
  }

  float invr[4];
#pragma unroll
  for (int r = 0; r < 4; ++r) invr[r] = 1.f / lrun[r];
#pragma unroll
  for (int nf2 = 0; nf2 < 8; ++nf2) {
    const int d = nf2 * 16 + l15;
#pragma unroll
    for (int r = 0; r < 4; ++r) {
      const int srow = qw0 + l4 * 4 + r;
      ctx[(size_t)srow * H + h * HD + d] = f2bf(of[nf2][r] * invr[r]);
    }
  }
}

// ---------------------------------------------------------------------------
extern "C" void kernel_launch(void* const* d_in, const int* in_sizes, int n_in,
                              void* d_out, int out_size, void* d_ws, size_t ws_size,
                              hipStream_t stream) {
  (void)in_sizes; (void)n_in; (void)out_size; (void)ws_size;
  const float* hidden  = (const float*)d_in[0];
  const float* w_qkv   = (const float*)d_in[4];
  const float* b_qkv   = (const float*)d_in[5];
  const float* w_dense = (const float*)d_in[6];
  const float* b_dense = (const float*)d_in[7];
  float* out = (float*)d_out;

  char* ws = (char*)d_ws;
  u16* wqkvb   = (u16*)(ws + 0);                       // 100.66 MB (0..100663296)
  u16* ctxb    = (u16*)(ws + 41943040);                // 16.78 MB (after QKV; wqkvb dead)
  u16* hb      = (u16*)(ws + 100663296);               // 16.78 MB
  u16* qkvb    = (u16*)(ws + 117440512);               // 50.33 MB
  u16* Qbp     = (u16*)(ws + 167772160);               // 16.78 MB
  u16* Kbp     = (u16*)(ws + 184549376);               // 16.78 MB
  u16* Vtp     = (u16*)(ws + 201326592);               // 16.78 MB
  u16* wdenseb = (u16*)(ws + 218103808);               // 33.55 MB, ends 251.7 MB

  cast_all<<<2048, 256, 0, stream>>>(w_qkv, hidden, w_dense, wqkvb, hb, wdenseb);
  // QKV hybrid split (r16 measured-best config):
  //   cols 0..8191:     gemm256 (256x256) -> 8 x 32 = 256 blocks
  //   cols 8192..12287: gemm8p  (128x256) -> 16 x 16 = 256 blocks
  gemm256<H3, 1><<<dim3(256), 512, 0, stream>>>(hb, wqkvb, b_qkv, qkvb);
  gemm8p<H3, 1><<<dim3(256), 512, 0, stream>>>(
      hb, wqkvb + (size_t)8192 * 4096, b_qkv + 8192, (u16*)qkvb + 8192);
  rotary_fused<<<dim3(S / 64, NH), 256, 0, stream>>>(qkvb, Qbp, Kbp, Vtp);
  // attn: single-buffer 40KB (4 blocks/CU), balanced XCD mapping, defer-max
  attn<<<dim3(1024), 256, 0, stream>>>(Qbp, Kbp, Vtp, ctxb);
  // dense: gemm8p (128x256) -> 16 x 16 = 256 blocks = 1/CU exact
  gemm8p<H, 0><<<dim3(256), 512, 0, stream>>>(ctxb, wdenseb, b_dense, out);
}